// Round 1
// baseline (228.725 us; speedup 1.0000x reference)
//
#include <hip/hip_runtime.h>
#include <math.h>

// clDice loss, fully fused (R16 = R15 + dword-slim neighbor reads + bank pad).
// R15 counters: LDS/VALU balanced, SQ_LDS_BANK_CONFLICT 1.37e7 (~22us/CU).
// Changes:
//  (1) erode l/r and open left/right columns read only the dword actually
//      consumed (dw3 left, dw0 right): 20 b128 -> 20 b32 per task-pair;
//      LDS read bytes/round -46%, open column maxes now h2 (-36 pk instr).
//  (2) LDS pitch 20 -> 21 cells (pad col stores +inf). Old pitch: 80 dwords
//      == 16 mod 32, 4-row shift == 0 mod 32 -> erode row-quads / open
//      opr-groups in one wave alias banks 4-way on every b128. Pitch 84
//      dwords -> 2-way (free per m136). LDS 59.5KB/block, still 2 blocks/CU.
// Same structure otherwise: tile 128x64, aperture 160x88, 2 barriers/round,
// in-place per-image buffers, dice at load, skels in regs. Cone/OOB
// arguments unchanged (pad cells are +inf, read only by edge cells whose
// e_M already bounds their valid levels).

#define HH 1024
#define WW 1024
#define BATCH 8
#define HW (HH * WW)
#define NITER 10
#define TW 128
#define TH 64
#define AH 88                 // aperture rows (halo 12)
#define CXR 20                // real h8 cells per row (160 px, halo 16)
#define CXC 21                // LDS pitch in cells (+1 pad col: bank de-alias)
#define NCELL (AH * CXC)      // 1848
#define NQ 440                // erode quads per image (22 x 20)
#define NT 1024               // 16 waves
#define NBX 8
#define NBY 16
#define NBLK (NBX * NBY * BATCH)  // 1024

typedef _Float16 h8 __attribute__((ext_vector_type(8)));
typedef _Float16 h2 __attribute__((ext_vector_type(2)));
typedef unsigned int u32;
typedef u32 u4v __attribute__((ext_vector_type(4)));

#define MIN2(a, b) __builtin_elementwise_min(a, b)
#define MAX2(a, b) __builtin_elementwise_max(a, b)

__device__ __forceinline__ u32 alignb(u32 hi, u32 lo) {
    return (u32)((((unsigned long long)hi << 32) | lo) >> 16);
}
__device__ __forceinline__ u32 h2u(h2 v) { return __builtin_bit_cast(u32, v); }
__device__ __forceinline__ h2 uh2(u32 v) { return __builtin_bit_cast(h2, v); }
// result[j]=v[j-1], result[0]=left-neighbor elem7 (hi half of l3)
__device__ __forceinline__ h8 shl1(h8 v, u32 l3) {
    u4v d = __builtin_bit_cast(u4v, v);
    u4v r;
    r.x = alignb(d.x, l3); r.y = alignb(d.y, d.x);
    r.z = alignb(d.z, d.y); r.w = alignb(d.w, d.z);
    return __builtin_bit_cast(h8, r);
}
// result[j]=v[j+1], result[7]=right-neighbor elem0 (lo half of r0d)
__device__ __forceinline__ h8 shr1(h8 v, u32 r0d) {
    u4v d = __builtin_bit_cast(u4v, v);
    u4v r;
    r.x = alignb(d.y, d.x); r.y = alignb(d.z, d.y);
    r.z = alignb(d.w, d.z); r.w = alignb(r0d, d.w);
    return __builtin_bit_cast(h8, r);
}
__device__ __forceinline__ float sigm(float x) { return 1.0f / (1.0f + __expf(-x)); }
__device__ __forceinline__ int imin(int a, int b) { return a < b ? a : b; }
__device__ __forceinline__ int imax(int a, int b) { return a > b ? a : b; }

__global__ __launch_bounds__(NT) void cldice_mega_kernel(const float* __restrict__ logits,
                                                         const int* __restrict__ target,
                                                         float* __restrict__ partials) {
    __shared__ __align__(16) h8 bufO[NCELL];  // 28.9 KB
    __shared__ __align__(16) h8 bufT[NCELL];  // 28.9 KB
    __shared__ float red[96];

    const int tid = threadIdx.x;
    const int img = blockIdx.z;
    const int x0 = blockIdx.x * TW, y0 = blockIdx.y * TH;

    const _Float16 HIF = (_Float16)__builtin_inff();
    const h8 HI8 = (h8)HIF;
    const h8 LO8 = (h8)(-HIF);
    const h2 LO2 = (h2)(-HIF);
    const h8 Z8 = (h8)(_Float16)0;

    // ---- erode quad geometry (1 slot; 880 tasks) ----
    const bool has_e = tid < 2 * NQ;
    const bool e_im = tid >= NQ;
    int e_base = CXC, e_M = 0;
    bool e_rok[4] = {false, false, false, false};
    if (has_e) {
        int p = e_im ? tid - NQ : tid;
        int q = p / 20, c = p - (p / 20) * 20;
        int r = 1 + 4 * q;
        if (r > 83) r = 83;                 // last quad rows 83..86
        e_base = r * CXC + c;
        int cMx = imin(8 * c + 7, 159 - 8 * c);
#pragma unroll
        for (int k = 0; k < 4; ++k)
            e_M = imax(e_M, imin(imin(r + k, 87 - (r + k)), cMx));
        bool colOOB = (x0 == 0 && c < 2) || (x0 == WW - TW && c >= 18);
#pragma unroll
        for (int k = 0; k < 4; ++k)
            e_rok[k] = !colOOB && ((unsigned)(y0 - 12 + r + k) < HH);
    }

    // ---- open quad geometry (512 tasks = 2 img x 16 row-quads x 16 cells) ----
    const bool has_o = tid < 512;
    const int op = tid & 255;
    const bool oimg = (tid >= 256) && has_o;
    const int opr = op >> 4, oc = op & 15;      // opr 0..15, oc 0..15
    const int orow = 12 + 4 * opr;              // rows orow..orow+3 (12..75)
    const int ob = orow * CXC + 2 + oc;
    const bool rT = (y0 == 0 && opr == 0);
    const bool rB = (y0 == HH - TH && opr == 15);
    const bool cL = (x0 == 0 && oc == 0);
    const bool cR = (x0 == WW - TW && oc == 15);
    h8* obuf = oimg ? bufT : bufO;

    // ---- load both images (level 0), +inf out-of-image; dice at load ----
    float d_inter = 0.f, d_card = 0.f, d_st = 0.f;
#pragma unroll
    for (int s = 0; s < 2; ++s) {
        int li = tid + NT * s;
        if (li < NCELL) {
            int r = li / CXC, c = li - r * CXC;
            if (c >= CXR) {  // pad column: constant +inf, never rewritten
                bufO[li] = HI8;
                bufT[li] = HI8;
            } else {
                int gy = y0 - 12 + r, gx = x0 - 16 + 8 * c;
                bool gyok = (unsigned)gy < HH;
                float vo[8], vt[8];
                if (gyok && gx >= 0 && gx + 7 < WW) {
                    int g = img * HW + gy * WW + gx;
                    float4 a = *(const float4*)(logits + g);
                    float4 b = *(const float4*)(logits + g + 4);
                    vo[0] = sigm(a.x); vo[1] = sigm(a.y); vo[2] = sigm(a.z); vo[3] = sigm(a.w);
                    vo[4] = sigm(b.x); vo[5] = sigm(b.y); vo[6] = sigm(b.z); vo[7] = sigm(b.w);
                    int4 p = *(const int4*)(target + g);
                    int4 q = *(const int4*)(target + g + 4);
                    vt[0] = (float)p.x; vt[1] = (float)p.y; vt[2] = (float)p.z; vt[3] = (float)p.w;
                    vt[4] = (float)q.x; vt[5] = (float)q.y; vt[6] = (float)q.z; vt[7] = (float)q.w;
                } else {
#pragma unroll
                    for (int j = 0; j < 8; ++j) {
                        int gxx = gx + j;
                        if (gyok && (unsigned)gxx < WW) {
                            int g = img * HW + gy * WW + gxx;
                            vo[j] = sigm(logits[g]);
                            vt[j] = (float)target[g];
                        } else { vo[j] = INFINITY; vt[j] = INFINITY; }
                    }
                }
                h8 ho, ht;
#pragma unroll
                for (int j = 0; j < 8; ++j) { ho[j] = (_Float16)vo[j]; ht[j] = (_Float16)vt[j]; }
                bufO[li] = ho;
                bufT[li] = ht;
                if (r >= 12 && r < 76 && c >= 2 && c < 18) {
#pragma unroll
                    for (int j = 0; j < 8; ++j) {
                        d_inter += vo[j] * vt[j];
                        d_card += vo[j] + vt[j];
                        d_st += vt[j];
                    }
                }
            }
        }
    }
    __syncthreads();
    h8 imv[4], sk[4];
    if (has_o) {
#pragma unroll
        for (int k = 0; k < 4; ++k) imv[k] = obuf[ob + k * CXC];
    }
#pragma unroll
    for (int k = 0; k < 4; ++k) sk[k] = Z8;

    // ---- rounds L=1..11: erode both images in place; open -> delta -> skel ----
    for (int L = 1; L <= NITER + 1; ++L) {
        h8 eo[4];
        const bool act = has_e && (L <= e_M);
        if (act) {
            const h8* b = e_im ? bufT : bufO;
            const u32* bw = (const u32*)b;
            const int eb4 = 4 * e_base;
            h8 u  = b[e_base - CXC];
            h8 c0 = b[e_base],           c1 = b[e_base + CXC];
            h8 c2 = b[e_base + 2 * CXC], c3 = b[e_base + 3 * CXC];
            h8 d  = b[e_base + 4 * CXC];
            // neighbor cells: only dw3 (left) / dw0 (right) are consumed
            u32 l0 = bw[eb4 - 1],                l1 = bw[eb4 + 4 * CXC - 1];
            u32 l2 = bw[eb4 + 8 * CXC - 1],      l3 = bw[eb4 + 12 * CXC - 1];
            u32 r0 = bw[eb4 + 4],                r1 = bw[eb4 + 4 * CXC + 4];
            u32 r2 = bw[eb4 + 8 * CXC + 4],      r3 = bw[eb4 + 12 * CXC + 4];
            h8 p01 = MIN2(c0, c1), p12 = MIN2(c1, c2), p23 = MIN2(c2, c3);
            h8 v0 = MIN2(u, p01), v1 = MIN2(p01, c2), v2 = MIN2(p12, c3), v3 = MIN2(p23, d);
            eo[0] = MIN2(v0, MIN2(shl1(c0, l0), shr1(c0, r0)));
            eo[1] = MIN2(v1, MIN2(shl1(c1, l1), shr1(c1, r1)));
            eo[2] = MIN2(v2, MIN2(shl1(c2, l2), shr1(c2, r2)));
            eo[3] = MIN2(v3, MIN2(shl1(c3, l3), shr1(c3, r3)));
        }
        __syncthreads();  // all reads of level L-1 done
        if (act) {
            h8* b = e_im ? bufT : bufO;
#pragma unroll
            for (int k = 0; k < 4; ++k)
                b[e_base + k * CXC] = e_rok[k] ? eo[k] : HI8;
        }
        __syncthreads();  // level L published
        if (has_o) {
            const u32* ow = (const u32*)obuf;
            const int owb = 4 * ob;
            // center column rows orow-1..orow+4 (full cells)
            h8 m0 = obuf[ob - CXC], m1 = obuf[ob], m2 = obuf[ob + CXC];
            h8 m3 = obuf[ob + 2 * CXC], m4 = obuf[ob + 3 * CXC], m5 = obuf[ob + 4 * CXC];
            h8 nm0 = m1, nm1 = m2, nm2 = m3, nm3 = m4;  // level-L centers (unmasked)
            if (rT) m0 = LO8;
            if (rB) m5 = LO8;
            h8 q12 = MAX2(m1, m2), q34 = MAX2(m3, m4);
            h8 Mc0 = MAX2(m0, q12), Mc1 = MAX2(q12, m3);
            h8 Mc2 = MAX2(m2, q34), Mc3 = MAX2(q34, m5);
            // left column: only dw3 (elems 6,7) feeds shl1 -> h2 math
            h2 la0 = uh2(ow[owb - 4 * CXC - 1]), la1 = uh2(ow[owb - 1]);
            h2 la2 = uh2(ow[owb + 4 * CXC - 1]), la3 = uh2(ow[owb + 8 * CXC - 1]);
            h2 la4 = uh2(ow[owb + 12 * CXC - 1]), la5 = uh2(ow[owb + 16 * CXC - 1]);
            if (rT) la0 = LO2;
            if (rB) la5 = LO2;
            h2 s12 = MAX2(la1, la2), s34 = MAX2(la3, la4);
            h2 Ml0 = MAX2(la0, s12), Ml1 = MAX2(s12, la3);
            h2 Ml2 = MAX2(la2, s34), Ml3 = MAX2(s34, la5);
            if (cL) { Ml0 = LO2; Ml1 = LO2; Ml2 = LO2; Ml3 = LO2; }
            // right column: only dw0 (elems 0,1) feeds shr1 -> h2 math
            h2 rb0 = uh2(ow[owb - 4 * CXC + 4]), rb1 = uh2(ow[owb + 4]);
            h2 rb2 = uh2(ow[owb + 4 * CXC + 4]), rb3 = uh2(ow[owb + 8 * CXC + 4]);
            h2 rb4 = uh2(ow[owb + 12 * CXC + 4]), rb5 = uh2(ow[owb + 16 * CXC + 4]);
            if (rT) rb0 = LO2;
            if (rB) rb5 = LO2;
            h2 t12 = MAX2(rb1, rb2), t34 = MAX2(rb3, rb4);
            h2 Mr0 = MAX2(rb0, t12), Mr1 = MAX2(t12, rb3);
            h2 Mr2 = MAX2(rb2, t34), Mr3 = MAX2(t34, rb5);
            if (cR) { Mr0 = LO2; Mr1 = LO2; Mr2 = LO2; Mr3 = LO2; }
            h8 o0 = MAX2(Mc0, MAX2(shl1(Mc0, h2u(Ml0)), shr1(Mc0, h2u(Mr0))));
            h8 o1 = MAX2(Mc1, MAX2(shl1(Mc1, h2u(Ml1)), shr1(Mc1, h2u(Mr1))));
            h8 o2 = MAX2(Mc2, MAX2(shl1(Mc2, h2u(Ml2)), shr1(Mc2, h2u(Mr2))));
            h8 o3 = MAX2(Mc3, MAX2(shl1(Mc3, h2u(Ml3)), shr1(Mc3, h2u(Mr3))));
            h8 d0 = MAX2(imv[0] - o0, Z8);
            h8 d1 = MAX2(imv[1] - o1, Z8);
            h8 d2 = MAX2(imv[2] - o2, Z8);
            h8 d3 = MAX2(imv[3] - o3, Z8);
            if (L == 1) { sk[0] = d0; sk[1] = d1; sk[2] = d2; sk[3] = d3; }
            else {
                sk[0] = sk[0] + MAX2(d0 - sk[0] * d0, Z8);
                sk[1] = sk[1] + MAX2(d1 - sk[1] * d1, Z8);
                sk[2] = sk[2] + MAX2(d2 - sk[2] * d2, Z8);
                sk[3] = sk[3] + MAX2(d3 - sk[3] * d3, Z8);
            }
            imv[0] = nm0; imv[1] = nm1; imv[2] = nm2; imv[3] = nm3;
        }
        // no barrier: open reads and next round's erode reads are both level L
    }

    // ---- final skO*skT exchange (T-open threads publish into bufO head) ----
    __syncthreads();
    if (oimg) {
#pragma unroll
        for (int k = 0; k < 4; ++k) bufO[4 * op + k] = sk[k];
    }
    __syncthreads();
    float I = 0.f, So = 0.f, St = 0.f;
    if (has_o && !oimg) {
#pragma unroll
        for (int k = 0; k < 4; ++k) {
            h8 t = bufO[4 * op + k];
#pragma unroll
            for (int j = 0; j < 8; ++j) {
                float a = (float)sk[k][j], b = (float)t[j];
                I += a * b; So += a; St += b;
            }
        }
    }

    // ---- block reduce 6 values (16 waves) ----
    float v6[6] = {d_inter, d_card, d_st, I, So, St};
#pragma unroll
    for (int q = 0; q < 6; ++q)
        for (int off = 32; off > 0; off >>= 1) v6[q] += __shfl_down(v6[q], off);
    int lane = tid & 63, w = tid >> 6;
    if (lane == 0) {
#pragma unroll
        for (int q = 0; q < 6; ++q) red[w * 6 + q] = v6[q];
    }
    __syncthreads();
    if (tid == 0) {
        int bid = (blockIdx.z * gridDim.y + blockIdx.y) * gridDim.x + blockIdx.x;
#pragma unroll
        for (int q = 0; q < 6; ++q) {
            float s = 0.f;
#pragma unroll
            for (int ww = 0; ww < 16; ++ww) s += red[ww * 6 + q];
            partials[q * NBLK + bid] = s;
        }
    }
}

__global__ __launch_bounds__(1024) void final_kernel(const float* __restrict__ partials,
                                                     float* __restrict__ out) {
    float s[6] = {0.f, 0.f, 0.f, 0.f, 0.f, 0.f};
    for (int i = threadIdx.x; i < NBLK; i += 1024) {
#pragma unroll
        for (int q = 0; q < 6; ++q) s[q] += partials[q * NBLK + i];
    }
#pragma unroll
    for (int q = 0; q < 6; ++q)
        for (int off = 32; off > 0; off >>= 1) s[q] += __shfl_down(s[q], off);
    __shared__ float red[96];
    int lane = threadIdx.x & 63, w = threadIdx.x >> 6;
    if (lane == 0) {
#pragma unroll
        for (int q = 0; q < 6; ++q) red[w * 6 + q] = s[q];
    }
    __syncthreads();
    if (threadIdx.x == 0) {
        float t[6];
#pragma unroll
        for (int q = 0; q < 6; ++q) {
            float a = 0.f;
#pragma unroll
            for (int ww = 0; ww < 16; ++ww) a += red[ww * 6 + q];
            t[q] = a;
        }
        float inter = t[0], card = t[1], sumt = t[2];
        float I = t[3], So = t[4], St = t[5];
        float score_d = (2.0f * inter + 1.0f) / fmaxf(card + 1.0f, 1e-7f);
        float dice = (1.0f - score_d) * (sumt > 0.0f ? 1.0f : 0.0f);
        float tprec = (I + 1.0f) / (So + 1.0f);
        float tsens = (I + 1.0f) / (St + 1.0f);
        float score_c = 2.0f * (tprec * tsens) / (tprec + tsens);
        float cl = (1.0f - score_c) * (St > 0.0f ? 1.0f : 0.0f);
        out[0] = 0.5f * dice + 0.5f * cl;
    }
}

extern "C" void kernel_launch(void* const* d_in, const int* in_sizes, int n_in,
                              void* d_out, int out_size, void* d_ws, size_t ws_size,
                              hipStream_t stream) {
    const float* logits = (const float*)d_in[0];
    const int* target = (const int*)d_in[1];
    float* out = (float*)d_out;
    float* partials = (float*)d_ws;  // 6*NBLK floats, fully overwritten each call

    dim3 grid(NBX, NBY, BATCH);
    cldice_mega_kernel<<<grid, NT, 0, stream>>>(logits, target, partials);
    final_kernel<<<1, 1024, 0, stream>>>(partials, out);
}

// Round 2
// 227.627 us; speedup vs baseline: 1.0048x; 1.0048x over previous
//
#include <hip/hip_runtime.h>
#include <math.h>

// clDice loss, fully fused (R17 = R15 base + open-phase neighbor shuffles).
// R16 postmortem: slim b32 neighbor reads at odd dword offsets are ~4-way
// bank-aliased (conflicts 1.37e7 -> 1.62e7, +15us) -- reverted, pitch back
// to 20. R17: open lane oc's left/right column maxes Ml_k/Mr_k are exactly
// lane (oc-1)/(oc+1)'s center maxes Mc_k; only dw3/dw0 are consumed. So
// fetch them with 8 ds_bpermute_b32 (bankless crossbar) instead of 12 b128
// reads + 24 pk_max per open task. Edge lanes oc==0/15 coincide with tile
// halo (cells 1/18): predicated 6x b32 dword read + h2 max path. Open lanes
// are active all rounds (no cone gating) -> no staleness hazard. Erode side
// untouched (R15 form). Same tile 128x64, aperture 160x88, 2 barriers/round,
// in-place per-image buffers, dice at load, skels in regs.

#define HH 1024
#define WW 1024
#define BATCH 8
#define HW (HH * WW)
#define NITER 10
#define TW 128
#define TH 64
#define AH 88                 // aperture rows (halo 12)
#define CXC 20                // h8 cells per row (160 px, halo 16 = 2 cells)
#define NCELL (AH * CXC)      // 1760
#define NQ 440                // erode quads per image (22 x 20)
#define NT 1024               // 16 waves
#define NBX 8
#define NBY 16
#define NBLK (NBX * NBY * BATCH)  // 1024

typedef _Float16 h8 __attribute__((ext_vector_type(8)));
typedef _Float16 h2 __attribute__((ext_vector_type(2)));
typedef unsigned int u32;
typedef u32 u4v __attribute__((ext_vector_type(4)));

#define MIN2(a, b) __builtin_elementwise_min(a, b)
#define MAX2(a, b) __builtin_elementwise_max(a, b)

__device__ __forceinline__ u32 alignb(u32 hi, u32 lo) {
    return (u32)((((unsigned long long)hi << 32) | lo) >> 16);
}
__device__ __forceinline__ u32 dw0(h8 v) { return __builtin_bit_cast(u4v, v).x; }
__device__ __forceinline__ u32 dw3(h8 v) { return __builtin_bit_cast(u4v, v).w; }
__device__ __forceinline__ u32 h2u(h2 v) { return __builtin_bit_cast(u32, v); }
__device__ __forceinline__ h2 uh2(u32 v) { return __builtin_bit_cast(h2, v); }
// result[j]=v[j-1], result[0]=left-neighbor elem7 (hi half of l3)
__device__ __forceinline__ h8 shl1(h8 v, u32 l3) {
    u4v d = __builtin_bit_cast(u4v, v);
    u4v r;
    r.x = alignb(d.x, l3); r.y = alignb(d.y, d.x);
    r.z = alignb(d.z, d.y); r.w = alignb(d.w, d.z);
    return __builtin_bit_cast(h8, r);
}
// result[j]=v[j+1], result[7]=right-neighbor elem0 (lo half of r0d)
__device__ __forceinline__ h8 shr1(h8 v, u32 r0d) {
    u4v d = __builtin_bit_cast(u4v, v);
    u4v r;
    r.x = alignb(d.y, d.x); r.y = alignb(d.z, d.y);
    r.z = alignb(d.w, d.z); r.w = alignb(r0d, d.w);
    return __builtin_bit_cast(h8, r);
}
__device__ __forceinline__ float sigm(float x) { return 1.0f / (1.0f + __expf(-x)); }
__device__ __forceinline__ int imin(int a, int b) { return a < b ? a : b; }
__device__ __forceinline__ int imax(int a, int b) { return a > b ? a : b; }

__global__ __launch_bounds__(NT) void cldice_mega_kernel(const float* __restrict__ logits,
                                                         const int* __restrict__ target,
                                                         float* __restrict__ partials) {
    __shared__ __align__(16) h8 bufO[NCELL];  // 28.2 KB
    __shared__ __align__(16) h8 bufT[NCELL];  // 28.2 KB
    __shared__ float red[96];

    const int tid = threadIdx.x;
    const int img = blockIdx.z;
    const int x0 = blockIdx.x * TW, y0 = blockIdx.y * TH;

    const _Float16 HIF = (_Float16)__builtin_inff();
    const h8 HI8 = (h8)HIF;
    const h8 LO8 = (h8)(-HIF);
    const h2 LO2 = (h2)(-HIF);
    const h8 Z8 = (h8)(_Float16)0;

    // lane-shuffle byte addresses (bpermute: lane*4), computed once
    const int lane0 = tid & 63;
    const int aL = ((lane0 - 1) & 63) << 2;
    const int aR = ((lane0 + 1) & 63) << 2;

    // ---- erode quad geometry (1 slot; 880 tasks) ----
    const bool has_e = tid < 2 * NQ;
    const bool e_im = tid >= NQ;
    int e_base = CXC, e_M = 0;
    bool e_rok[4] = {false, false, false, false};
    if (has_e) {
        int p = e_im ? tid - NQ : tid;
        int q = p / 20, c = p - (p / 20) * 20;
        int r = 1 + 4 * q;
        if (r > 83) r = 83;                 // last quad rows 83..86
        e_base = r * CXC + c;
        int cMx = imin(8 * c + 7, 159 - 8 * c);
#pragma unroll
        for (int k = 0; k < 4; ++k)
            e_M = imax(e_M, imin(imin(r + k, 87 - (r + k)), cMx));
        bool colOOB = (x0 == 0 && c < 2) || (x0 == WW - TW && c >= 18);
#pragma unroll
        for (int k = 0; k < 4; ++k)
            e_rok[k] = !colOOB && ((unsigned)(y0 - 12 + r + k) < HH);
    }

    // ---- open quad geometry (512 tasks = 2 img x 16 row-quads x 16 cells) ----
    const bool has_o = tid < 512;
    const int op = tid & 255;
    const bool oimg = (tid >= 256) && has_o;
    const int opr = op >> 4, oc = op & 15;      // opr 0..15, oc 0..15
    const int orow = 12 + 4 * opr;              // rows orow..orow+3 (12..75)
    const int ob = orow * CXC + 2 + oc;
    const bool rT = (y0 == 0 && opr == 0);
    const bool rB = (y0 == HH - TH && opr == 15);
    const bool cL = (x0 == 0 && oc == 0);
    const bool cR = (x0 == WW - TW && oc == 15);
    h8* obuf = oimg ? bufT : bufO;

    // ---- load both images (level 0), +inf out-of-image; dice at load ----
    float d_inter = 0.f, d_card = 0.f, d_st = 0.f;
#pragma unroll
    for (int s = 0; s < 2; ++s) {
        int li = tid + NT * s;
        if (li < NCELL) {
            int r = li / CXC, c = li - r * CXC;
            int gy = y0 - 12 + r, gx = x0 - 16 + 8 * c;
            bool gyok = (unsigned)gy < HH;
            float vo[8], vt[8];
            if (gyok && gx >= 0 && gx + 7 < WW) {
                int g = img * HW + gy * WW + gx;
                float4 a = *(const float4*)(logits + g);
                float4 b = *(const float4*)(logits + g + 4);
                vo[0] = sigm(a.x); vo[1] = sigm(a.y); vo[2] = sigm(a.z); vo[3] = sigm(a.w);
                vo[4] = sigm(b.x); vo[5] = sigm(b.y); vo[6] = sigm(b.z); vo[7] = sigm(b.w);
                int4 p = *(const int4*)(target + g);
                int4 q = *(const int4*)(target + g + 4);
                vt[0] = (float)p.x; vt[1] = (float)p.y; vt[2] = (float)p.z; vt[3] = (float)p.w;
                vt[4] = (float)q.x; vt[5] = (float)q.y; vt[6] = (float)q.z; vt[7] = (float)q.w;
            } else {
#pragma unroll
                for (int j = 0; j < 8; ++j) {
                    int gxx = gx + j;
                    if (gyok && (unsigned)gxx < WW) {
                        int g = img * HW + gy * WW + gxx;
                        vo[j] = sigm(logits[g]);
                        vt[j] = (float)target[g];
                    } else { vo[j] = INFINITY; vt[j] = INFINITY; }
                }
            }
            h8 ho, ht;
#pragma unroll
            for (int j = 0; j < 8; ++j) { ho[j] = (_Float16)vo[j]; ht[j] = (_Float16)vt[j]; }
            bufO[li] = ho;
            bufT[li] = ht;
            if (r >= 12 && r < 76 && c >= 2 && c < 18) {
#pragma unroll
                for (int j = 0; j < 8; ++j) {
                    d_inter += vo[j] * vt[j];
                    d_card += vo[j] + vt[j];
                    d_st += vt[j];
                }
            }
        }
    }
    __syncthreads();
    h8 imv[4], sk[4];
    if (has_o) {
#pragma unroll
        for (int k = 0; k < 4; ++k) imv[k] = obuf[ob + k * CXC];
    }
#pragma unroll
    for (int k = 0; k < 4; ++k) sk[k] = Z8;

    // ---- rounds L=1..11: erode both images in place; open -> delta -> skel ----
    for (int L = 1; L <= NITER + 1; ++L) {
        h8 eo[4];
        const bool act = has_e && (L <= e_M);
        if (act) {
            const h8* b = e_im ? bufT : bufO;
            h8 u  = b[e_base - CXC];
            h8 c0 = b[e_base],           c1 = b[e_base + CXC];
            h8 c2 = b[e_base + 2 * CXC], c3 = b[e_base + 3 * CXC];
            h8 d  = b[e_base + 4 * CXC];
            h8 l0 = b[e_base - 1],           l1 = b[e_base + CXC - 1];
            h8 l2 = b[e_base + 2 * CXC - 1], l3 = b[e_base + 3 * CXC - 1];
            h8 r0 = b[e_base + 1],           r1 = b[e_base + CXC + 1];
            h8 r2 = b[e_base + 2 * CXC + 1], r3 = b[e_base + 3 * CXC + 1];
            h8 p01 = MIN2(c0, c1), p12 = MIN2(c1, c2), p23 = MIN2(c2, c3);
            h8 v0 = MIN2(u, p01), v1 = MIN2(p01, c2), v2 = MIN2(p12, c3), v3 = MIN2(p23, d);
            eo[0] = MIN2(v0, MIN2(shl1(c0, dw3(l0)), shr1(c0, dw0(r0))));
            eo[1] = MIN2(v1, MIN2(shl1(c1, dw3(l1)), shr1(c1, dw0(r1))));
            eo[2] = MIN2(v2, MIN2(shl1(c2, dw3(l2)), shr1(c2, dw0(r2))));
            eo[3] = MIN2(v3, MIN2(shl1(c3, dw3(l3)), shr1(c3, dw0(r3))));
        }
        __syncthreads();  // all reads of level L-1 done
        if (act) {
            h8* b = e_im ? bufT : bufO;
#pragma unroll
            for (int k = 0; k < 4; ++k)
                b[e_base + k * CXC] = e_rok[k] ? eo[k] : HI8;
        }
        __syncthreads();  // level L published
        if (has_o) {
            // center column rows orow-1..orow+4
            h8 m0 = obuf[ob - CXC], m1 = obuf[ob], m2 = obuf[ob + CXC];
            h8 m3 = obuf[ob + 2 * CXC], m4 = obuf[ob + 3 * CXC], m5 = obuf[ob + 4 * CXC];
            h8 nm0 = m1, nm1 = m2, nm2 = m3, nm3 = m4;  // level-L centers (unmasked)
            if (rT) m0 = LO8;
            if (rB) m5 = LO8;
            h8 q12 = MAX2(m1, m2), q34 = MAX2(m3, m4);
            h8 Mc0 = MAX2(m0, q12), Mc1 = MAX2(q12, m3);
            h8 Mc2 = MAX2(m2, q34), Mc3 = MAX2(q34, m5);
            // neighbor column maxes via lane shuffle: Ml_k = Mc_k(lane-1),
            // Mr_k = Mc_k(lane+1); only dw3 (left) / dw0 (right) consumed.
            u32 ml0 = (u32)__builtin_amdgcn_ds_bpermute(aL, (int)dw3(Mc0));
            u32 ml1 = (u32)__builtin_amdgcn_ds_bpermute(aL, (int)dw3(Mc1));
            u32 ml2 = (u32)__builtin_amdgcn_ds_bpermute(aL, (int)dw3(Mc2));
            u32 ml3 = (u32)__builtin_amdgcn_ds_bpermute(aL, (int)dw3(Mc3));
            u32 mr0 = (u32)__builtin_amdgcn_ds_bpermute(aR, (int)dw0(Mc0));
            u32 mr1 = (u32)__builtin_amdgcn_ds_bpermute(aR, (int)dw0(Mc1));
            u32 mr2 = (u32)__builtin_amdgcn_ds_bpermute(aR, (int)dw0(Mc2));
            u32 mr3 = (u32)__builtin_amdgcn_ds_bpermute(aR, (int)dw0(Mc3));
            if (oc == 0) {
                if (cL) {
                    ml0 = h2u(LO2); ml1 = h2u(LO2); ml2 = h2u(LO2); ml3 = h2u(LO2);
                } else {
                    // halo column = cell 1, rows orow-1..orow+4, dw3 only
                    const u32* ow = (const u32*)obuf;
                    const int hb = 4 * (ob - 1) + 3;
                    h2 a0 = uh2(ow[hb - 4 * CXC]), a1 = uh2(ow[hb]);
                    h2 a2 = uh2(ow[hb + 4 * CXC]), a3 = uh2(ow[hb + 8 * CXC]);
                    h2 a4 = uh2(ow[hb + 12 * CXC]), a5 = uh2(ow[hb + 16 * CXC]);
                    if (rT) a0 = LO2;
                    if (rB) a5 = LO2;
                    h2 s12 = MAX2(a1, a2), s34 = MAX2(a3, a4);
                    ml0 = h2u(MAX2(a0, s12)); ml1 = h2u(MAX2(s12, a3));
                    ml2 = h2u(MAX2(a2, s34)); ml3 = h2u(MAX2(s34, a5));
                }
            }
            if (oc == 15) {
                if (cR) {
                    mr0 = h2u(LO2); mr1 = h2u(LO2); mr2 = h2u(LO2); mr3 = h2u(LO2);
                } else {
                    // halo column = cell 18, rows orow-1..orow+4, dw0 only
                    const u32* ow = (const u32*)obuf;
                    const int hb = 4 * (ob + 1);
                    h2 b0 = uh2(ow[hb - 4 * CXC]), b1 = uh2(ow[hb]);
                    h2 b2 = uh2(ow[hb + 4 * CXC]), b3 = uh2(ow[hb + 8 * CXC]);
                    h2 b4 = uh2(ow[hb + 12 * CXC]), b5 = uh2(ow[hb + 16 * CXC]);
                    if (rT) b0 = LO2;
                    if (rB) b5 = LO2;
                    h2 t12 = MAX2(b1, b2), t34 = MAX2(b3, b4);
                    mr0 = h2u(MAX2(b0, t12)); mr1 = h2u(MAX2(t12, b3));
                    mr2 = h2u(MAX2(b2, t34)); mr3 = h2u(MAX2(t34, b5));
                }
            }
            h8 o0 = MAX2(Mc0, MAX2(shl1(Mc0, ml0), shr1(Mc0, mr0)));
            h8 o1 = MAX2(Mc1, MAX2(shl1(Mc1, ml1), shr1(Mc1, mr1)));
            h8 o2 = MAX2(Mc2, MAX2(shl1(Mc2, ml2), shr1(Mc2, mr2)));
            h8 o3 = MAX2(Mc3, MAX2(shl1(Mc3, ml3), shr1(Mc3, mr3)));
            h8 d0 = MAX2(imv[0] - o0, Z8);
            h8 d1 = MAX2(imv[1] - o1, Z8);
            h8 d2 = MAX2(imv[2] - o2, Z8);
            h8 d3 = MAX2(imv[3] - o3, Z8);
            if (L == 1) { sk[0] = d0; sk[1] = d1; sk[2] = d2; sk[3] = d3; }
            else {
                sk[0] = sk[0] + MAX2(d0 - sk[0] * d0, Z8);
                sk[1] = sk[1] + MAX2(d1 - sk[1] * d1, Z8);
                sk[2] = sk[2] + MAX2(d2 - sk[2] * d2, Z8);
                sk[3] = sk[3] + MAX2(d3 - sk[3] * d3, Z8);
            }
            imv[0] = nm0; imv[1] = nm1; imv[2] = nm2; imv[3] = nm3;
        }
        // no barrier: open reads and next round's erode reads are both level L
    }

    // ---- final skO*skT exchange (T-open threads publish into bufO head) ----
    __syncthreads();
    if (oimg) {
#pragma unroll
        for (int k = 0; k < 4; ++k) bufO[4 * op + k] = sk[k];
    }
    __syncthreads();
    float I = 0.f, So = 0.f, St = 0.f;
    if (has_o && !oimg) {
#pragma unroll
        for (int k = 0; k < 4; ++k) {
            h8 t = bufO[4 * op + k];
#pragma unroll
            for (int j = 0; j < 8; ++j) {
                float a = (float)sk[k][j], b = (float)t[j];
                I += a * b; So += a; St += b;
            }
        }
    }

    // ---- block reduce 6 values (16 waves) ----
    float v6[6] = {d_inter, d_card, d_st, I, So, St};
#pragma unroll
    for (int q = 0; q < 6; ++q)
        for (int off = 32; off > 0; off >>= 1) v6[q] += __shfl_down(v6[q], off);
    int lane = tid & 63, w = tid >> 6;
    if (lane == 0) {
#pragma unroll
        for (int q = 0; q < 6; ++q) red[w * 6 + q] = v6[q];
    }
    __syncthreads();
    if (tid == 0) {
        int bid = (blockIdx.z * gridDim.y + blockIdx.y) * gridDim.x + blockIdx.x;
#pragma unroll
        for (int q = 0; q < 6; ++q) {
            float s = 0.f;
#pragma unroll
            for (int ww = 0; ww < 16; ++ww) s += red[ww * 6 + q];
            partials[q * NBLK + bid] = s;
        }
    }
}

__global__ __launch_bounds__(1024) void final_kernel(const float* __restrict__ partials,
                                                     float* __restrict__ out) {
    float s[6] = {0.f, 0.f, 0.f, 0.f, 0.f, 0.f};
    for (int i = threadIdx.x; i < NBLK; i += 1024) {
#pragma unroll
        for (int q = 0; q < 6; ++q) s[q] += partials[q * NBLK + i];
    }
#pragma unroll
    for (int q = 0; q < 6; ++q)
        for (int off = 32; off > 0; off >>= 1) s[q] += __shfl_down(s[q], off);
    __shared__ float red[96];
    int lane = threadIdx.x & 63, w = threadIdx.x >> 6;
    if (lane == 0) {
#pragma unroll
        for (int q = 0; q < 6; ++q) red[w * 6 + q] = s[q];
    }
    __syncthreads();
    if (threadIdx.x == 0) {
        float t[6];
#pragma unroll
        for (int q = 0; q < 6; ++q) {
            float a = 0.f;
#pragma unroll
            for (int ww = 0; ww < 16; ++ww) a += red[ww * 6 + q];
            t[q] = a;
        }
        float inter = t[0], card = t[1], sumt = t[2];
        float I = t[3], So = t[4], St = t[5];
        float score_d = (2.0f * inter + 1.0f) / fmaxf(card + 1.0f, 1e-7f);
        float dice = (1.0f - score_d) * (sumt > 0.0f ? 1.0f : 0.0f);
        float tprec = (I + 1.0f) / (So + 1.0f);
        float tsens = (I + 1.0f) / (St + 1.0f);
        float score_c = 2.0f * (tprec * tsens) / (tprec + tsens);
        float cl = (1.0f - score_c) * (St > 0.0f ? 1.0f : 0.0f);
        out[0] = 0.5f * dice + 0.5f * cl;
    }
}

extern "C" void kernel_launch(void* const* d_in, const int* in_sizes, int n_in,
                              void* d_out, int out_size, void* d_ws, size_t ws_size,
                              hipStream_t stream) {
    const float* logits = (const float*)d_in[0];
    const int* target = (const int*)d_in[1];
    float* out = (float*)d_out;
    float* partials = (float*)d_ws;  // 6*NBLK floats, fully overwritten each call

    dim3 grid(NBX, NBY, BATCH);
    cldice_mega_kernel<<<grid, NT, 0, stream>>>(logits, target, partials);
    final_kernel<<<1, 1024, 0, stream>>>(partials, out);
}

// Round 3
// 181.227 us; speedup vs baseline: 1.2621x; 1.2560x over previous
//
#include <hip/hip_runtime.h>
#include <math.h>

// clDice loss, fully fused (R18 = R15 O-side + BITBOARD T-side).
// R16/R17 postmortem: VALU(90us) + LDS(60us) are ADDITIVE (barrier lockstep
// phase-serializes pipes); micro-opts of open LDS failed twice. R18 removes
// ~half of both totals: target is binary and stays binary under soft
// morphology, so the whole T pipeline becomes bit-ops at 32px/dword:
//   erode = AND of 5-px cross, dilate = OR of 3x3, skel: sk |= im & ~open.
// T bitmap: 88 rows x 6 dwords (192 bits: aperture px p at bit p+16; pre/post
// pad bits forced 1 = +inf analog for erode; re-forced per level via oobm).
// T-erode: 132 tasks (22 quads x 6 dwords), T-open: 64 tasks (16 quads x 4
// interior dwords). Horizontal shift-by-1 = v_alignbit carry funnel.
// Waves now disjoint: O-erode 0-6, O-open 8-11, T-erode 12-14, T-open 15.
// Exact arithmetic on T (bits == fp16 values) -> numerics unchanged.
// O-side identical to R15. Same tile 128x64, aperture 160x88, 2 barriers/rnd.

#define HH 1024
#define WW 1024
#define BATCH 8
#define HW (HH * WW)
#define NITER 10
#define TW 128
#define TH 64
#define AH 88                 // aperture rows (halo 12)
#define CXC 20                // h8 cells per row (160 px, halo 16 = 2 cells)
#define NCELL (AH * CXC)      // 1760
#define BMP 6                 // T bitmap pitch (dwords/row, 192 bits)
#define NQO 440               // O erode quads (22 x 20)
#define NT 1024               // 16 waves
#define NBX 8
#define NBY 16
#define NBLK (NBX * NBY * BATCH)  // 1024

typedef _Float16 h8 __attribute__((ext_vector_type(8)));
typedef unsigned int u32;
typedef unsigned long long u64;
typedef u32 u4v __attribute__((ext_vector_type(4)));

#define MIN2(a, b) __builtin_elementwise_min(a, b)
#define MAX2(a, b) __builtin_elementwise_max(a, b)

__device__ __forceinline__ u32 alignb(u32 hi, u32 lo) {
    return (u32)((((u64)hi << 32) | lo) >> 16);
}
__device__ __forceinline__ u32 fsh(u32 hi, u32 lo, int s) {
    return (u32)((((u64)hi << 32) | lo) >> s);  // v_alignbit_b32
}
__device__ __forceinline__ u32 dw0(h8 v) { return __builtin_bit_cast(u4v, v).x; }
__device__ __forceinline__ u32 dw3(h8 v) { return __builtin_bit_cast(u4v, v).w; }
// result[j]=v[j-1], result[0]=left-neighbor elem7 (hi half of l3)
__device__ __forceinline__ h8 shl1(h8 v, u32 l3) {
    u4v d = __builtin_bit_cast(u4v, v);
    u4v r;
    r.x = alignb(d.x, l3); r.y = alignb(d.y, d.x);
    r.z = alignb(d.z, d.y); r.w = alignb(d.w, d.z);
    return __builtin_bit_cast(h8, r);
}
// result[j]=v[j+1], result[7]=right-neighbor elem0 (lo half of r0d)
__device__ __forceinline__ h8 shr1(h8 v, u32 r0d) {
    u4v d = __builtin_bit_cast(u4v, v);
    u4v r;
    r.x = alignb(d.y, d.x); r.y = alignb(d.z, d.y);
    r.z = alignb(d.w, d.z); r.w = alignb(r0d, d.w);
    return __builtin_bit_cast(h8, r);
}
__device__ __forceinline__ float sigm(float x) { return 1.0f / (1.0f + __expf(-x)); }
__device__ __forceinline__ int imin(int a, int b) { return a < b ? a : b; }
__device__ __forceinline__ int imax(int a, int b) { return a > b ? a : b; }

__global__ __launch_bounds__(NT) void cldice_mega_kernel(const float* __restrict__ logits,
                                                         const int* __restrict__ target,
                                                         float* __restrict__ partials) {
    __shared__ __align__(16) h8 bufO[NCELL];   // 28.2 KB
    __shared__ u32 bmT[AH * BMP];              // 2.1 KB bitboard
    __shared__ u32 pub[256];                   // skT publish (64 tasks x 4)
    __shared__ float red[96];

    const int tid = threadIdx.x;
    const int img = blockIdx.z;
    const int x0 = blockIdx.x * TW, y0 = blockIdx.y * TH;

    const _Float16 HIF = (_Float16)__builtin_inff();
    const h8 HI8 = (h8)HIF;
    const h8 LO8 = (h8)(-HIF);
    const h8 Z8 = (h8)(_Float16)0;

    // ---- O-erode geometry (440 tasks, tid 0..439) ----
    const bool has_e = tid < NQO;
    int e_base = CXC, e_M = 0;
    bool e_rok[4] = {false, false, false, false};
    if (has_e) {
        int q = tid / 20, c = tid - (tid / 20) * 20;
        int r = 1 + 4 * q;
        if (r > 83) r = 83;                 // last quad rows 83..86
        e_base = r * CXC + c;
        int cMx = imin(8 * c + 7, 159 - 8 * c);
#pragma unroll
        for (int k = 0; k < 4; ++k)
            e_M = imax(e_M, imin(imin(r + k, 87 - (r + k)), cMx));
        bool colOOB = (x0 == 0 && c < 2) || (x0 == WW - TW && c >= 18);
#pragma unroll
        for (int k = 0; k < 4; ++k)
            e_rok[k] = !colOOB && ((unsigned)(y0 - 12 + r + k) < HH);
    }

    // ---- O-open geometry (256 tasks, tid 512..767) ----
    const bool has_o = (tid >= 512) && (tid < 768);
    const int op = tid & 255;
    const int opr = op >> 4, oc = op & 15;      // opr 0..15, oc 0..15
    const int orow = 12 + 4 * opr;              // rows orow..orow+3 (12..75)
    const int ob = orow * CXC + 2 + oc;
    const bool rT = (y0 == 0 && opr == 0);
    const bool rB = (y0 == HH - TH && opr == 15);
    const bool cL = (x0 == 0 && oc == 0);
    const bool cR = (x0 == WW - TW && oc == 15);

    // ---- T-erode-bit geometry (132 tasks, tid 768..899) ----
    const bool has_te = (tid >= 768) && (tid < 768 + 22 * BMP);
    int tb = BMP, te_M = 0;
    u32 oobm = 0;
    bool trok[4] = {false, false, false, false};
    if (has_te) {
        int p = tid - 768;
        int q = p / BMP, c = p - (p / BMP) * BMP;
        int r = 1 + 4 * q;
        if (r > 83) r = 83;
        tb = r * BMP + c;
        // dword c covers aperture px [32c-16, 32c+15]
        int pxlo = imax(32 * c - 16, 0), pxhi = imin(32 * c + 15, 159);
        int cMx = imin(pxhi, 159 - pxlo);
#pragma unroll
        for (int k = 0; k < 4; ++k)
            te_M = imax(te_M, imin(imin(r + k, 87 - (r + k)), cMx));
        if (c == 0) oobm |= 0x0000FFFFu;                 // pre-pad bits
        if (c == 5) oobm |= 0xFFFF0000u;                 // post-pad bits
        if (x0 == 0 && c == 0) oobm = 0xFFFFFFFFu;       // px 0..15 OOB
        if (x0 == WW - TW && c == 5) oobm = 0xFFFFFFFFu; // px 144..159 OOB
#pragma unroll
        for (int k = 0; k < 4; ++k)
            trok[k] = (unsigned)(y0 - 12 + r + k) < HH;
    }

    // ---- T-open-bit geometry (64 tasks, tid 960..1023) ----
    const bool has_to = tid >= 960;
    const int tp = tid - 960;
    const int topr = (tp >> 2) & 15, td = (tp & 3) + 1;  // dwords 1..4
    const int torow = 12 + 4 * topr;
    const int tob = torow * BMP + td;
    const bool trT = (y0 == 0 && topr == 0);
    const bool trB = (y0 == HH - TH && topr == 15);
    const bool tcL = (x0 == 0 && td == 1);
    const bool tcR = (x0 == WW - TW && td == 4);

    // ---- bitmap pads: bits 0-15 / 176-191 of each row = 1 (erode +inf) ----
    if (tid < AH) {
        unsigned short* p16 = (unsigned short*)bmT;
        p16[tid * 12 + 0] = 0xFFFFu;
        p16[tid * 12 + 11] = 0xFFFFu;
    }

    // ---- load: O image (sigmoid h8), T bitboard; dice at load ----
    float d_inter = 0.f, d_card = 0.f, d_st = 0.f;
#pragma unroll
    for (int s = 0; s < 2; ++s) {
        int li = tid + NT * s;
        if (li < NCELL) {
            int r = li / CXC, c = li - (li / CXC) * CXC;
            int gy = y0 - 12 + r, gx = x0 - 16 + 8 * c;
            bool gyok = (unsigned)gy < HH;
            float vo[8];
            u32 tb8 = 0;  // 8 target bits (1 = fg or OOB)
            if (gyok && gx >= 0 && gx + 7 < WW) {
                int g = img * HW + gy * WW + gx;
                float4 a = *(const float4*)(logits + g);
                float4 b = *(const float4*)(logits + g + 4);
                vo[0] = sigm(a.x); vo[1] = sigm(a.y); vo[2] = sigm(a.z); vo[3] = sigm(a.w);
                vo[4] = sigm(b.x); vo[5] = sigm(b.y); vo[6] = sigm(b.z); vo[7] = sigm(b.w);
                int4 p = *(const int4*)(target + g);
                int4 q = *(const int4*)(target + g + 4);
                tb8 = (p.x != 0 ? 1u : 0u) | (p.y != 0 ? 2u : 0u) |
                      (p.z != 0 ? 4u : 0u) | (p.w != 0 ? 8u : 0u) |
                      (q.x != 0 ? 16u : 0u) | (q.y != 0 ? 32u : 0u) |
                      (q.z != 0 ? 64u : 0u) | (q.w != 0 ? 128u : 0u);
            } else {
#pragma unroll
                for (int j = 0; j < 8; ++j) {
                    int gxx = gx + j;
                    if (gyok && (unsigned)gxx < WW) {
                        int g = img * HW + gy * WW + gxx;
                        vo[j] = sigm(logits[g]);
                        tb8 |= (target[g] != 0 ? 1u : 0u) << j;
                    } else { vo[j] = INFINITY; tb8 |= 1u << j; }
                }
            }
            h8 ho;
#pragma unroll
            for (int j = 0; j < 8; ++j) ho[j] = (_Float16)vo[j];
            bufO[li] = ho;
            ((unsigned char*)bmT)[r * 24 + 2 + c] = (unsigned char)tb8;
            if (r >= 12 && r < 76 && c >= 2 && c < 18) {
#pragma unroll
                for (int j = 0; j < 8; ++j) {
                    float t = (float)((tb8 >> j) & 1u);
                    d_inter += t * vo[j];
                    d_card += vo[j] + t;
                    d_st += t;
                }
            }
        }
    }
    __syncthreads();
    h8 imv[4], sk[4];
    if (has_o) {
#pragma unroll
        for (int k = 0; k < 4; ++k) imv[k] = bufO[ob + k * CXC];
    }
#pragma unroll
    for (int k = 0; k < 4; ++k) sk[k] = Z8;
    u32 timv[4] = {0, 0, 0, 0}, tsk[4] = {0, 0, 0, 0};
    if (has_to) {
#pragma unroll
        for (int k = 0; k < 4; ++k) timv[k] = bmT[tob + k * BMP];
    }

    // ---- rounds L=1..11 ----
    for (int L = 1; L <= NITER + 1; ++L) {
        // O-erode read+compute (h8)
        h8 eo[4];
        const bool act = has_e && (L <= e_M);
        if (act) {
            const h8* b = bufO;
            h8 u  = b[e_base - CXC];
            h8 c0 = b[e_base],           c1 = b[e_base + CXC];
            h8 c2 = b[e_base + 2 * CXC], c3 = b[e_base + 3 * CXC];
            h8 d  = b[e_base + 4 * CXC];
            h8 l0 = b[e_base - 1],           l1 = b[e_base + CXC - 1];
            h8 l2 = b[e_base + 2 * CXC - 1], l3 = b[e_base + 3 * CXC - 1];
            h8 r0 = b[e_base + 1],           r1 = b[e_base + CXC + 1];
            h8 r2 = b[e_base + 2 * CXC + 1], r3 = b[e_base + 3 * CXC + 1];
            h8 p01 = MIN2(c0, c1), p12 = MIN2(c1, c2), p23 = MIN2(c2, c3);
            h8 v0 = MIN2(u, p01), v1 = MIN2(p01, c2), v2 = MIN2(p12, c3), v3 = MIN2(p23, d);
            eo[0] = MIN2(v0, MIN2(shl1(c0, dw3(l0)), shr1(c0, dw0(r0))));
            eo[1] = MIN2(v1, MIN2(shl1(c1, dw3(l1)), shr1(c1, dw0(r1))));
            eo[2] = MIN2(v2, MIN2(shl1(c2, dw3(l2)), shr1(c2, dw0(r2))));
            eo[3] = MIN2(v3, MIN2(shl1(c3, dw3(l3)), shr1(c3, dw0(r3))));
        }
        // T-erode read+compute (bits): AND of 5-px cross
        u32 et[4];
        const bool actt = has_te && (L <= te_M);
        if (actt) {
            u32 m0 = bmT[tb - BMP], m1 = bmT[tb], m2 = bmT[tb + BMP];
            u32 m3 = bmT[tb + 2 * BMP], m4 = bmT[tb + 3 * BMP], m5 = bmT[tb + 4 * BMP];
            u32 lw0 = bmT[tb - 1],           lw1 = bmT[tb + BMP - 1];
            u32 lw2 = bmT[tb + 2 * BMP - 1], lw3 = bmT[tb + 3 * BMP - 1];
            u32 rw0 = bmT[tb + 1],           rw1 = bmT[tb + BMP + 1];
            u32 rw2 = bmT[tb + 2 * BMP + 1], rw3 = bmT[tb + 3 * BMP + 1];
            u32 p12 = m1 & m2, p23 = m2 & m3, p34 = m3 & m4;
            u32 v0 = m0 & p12, v1 = p12 & m3, v2 = p23 & m4, v3 = p34 & m5;
            et[0] = v0 & fsh(m1, lw0, 31) & fsh(rw0, m1, 1);
            et[1] = v1 & fsh(m2, lw1, 31) & fsh(rw1, m2, 1);
            et[2] = v2 & fsh(m3, lw2, 31) & fsh(rw2, m3, 1);
            et[3] = v3 & fsh(m4, lw3, 31) & fsh(rw3, m4, 1);
        }
        __syncthreads();  // all reads of level L-1 done
        if (act) {
#pragma unroll
            for (int k = 0; k < 4; ++k)
                bufO[e_base + k * CXC] = e_rok[k] ? eo[k] : HI8;
        }
        if (actt) {
#pragma unroll
            for (int k = 0; k < 4; ++k)
                bmT[tb + k * BMP] = trok[k] ? (et[k] | oobm) : 0xFFFFFFFFu;
        }
        __syncthreads();  // level L published
        // O-open (h8, R15 form)
        if (has_o) {
            h8 m0 = bufO[ob - CXC], m1 = bufO[ob], m2 = bufO[ob + CXC];
            h8 m3 = bufO[ob + 2 * CXC], m4 = bufO[ob + 3 * CXC], m5 = bufO[ob + 4 * CXC];
            h8 nm0 = m1, nm1 = m2, nm2 = m3, nm3 = m4;  // level-L centers (unmasked)
            if (rT) m0 = LO8;
            if (rB) m5 = LO8;
            h8 q12 = MAX2(m1, m2), q34 = MAX2(m3, m4);
            h8 Mc0 = MAX2(m0, q12), Mc1 = MAX2(q12, m3);
            h8 Mc2 = MAX2(m2, q34), Mc3 = MAX2(q34, m5);
            h8 a0 = bufO[ob - CXC - 1], a1 = bufO[ob - 1], a2 = bufO[ob + CXC - 1];
            h8 a3 = bufO[ob + 2 * CXC - 1], a4 = bufO[ob + 3 * CXC - 1], a5 = bufO[ob + 4 * CXC - 1];
            if (rT) a0 = LO8;
            if (rB) a5 = LO8;
            h8 s12 = MAX2(a1, a2), s34 = MAX2(a3, a4);
            h8 Ml0 = MAX2(a0, s12), Ml1 = MAX2(s12, a3);
            h8 Ml2 = MAX2(a2, s34), Ml3 = MAX2(s34, a5);
            if (cL) { Ml0 = LO8; Ml1 = LO8; Ml2 = LO8; Ml3 = LO8; }
            h8 b0 = bufO[ob - CXC + 1], b1 = bufO[ob + 1], b2 = bufO[ob + CXC + 1];
            h8 b3 = bufO[ob + 2 * CXC + 1], b4 = bufO[ob + 3 * CXC + 1], b5 = bufO[ob + 4 * CXC + 1];
            if (rT) b0 = LO8;
            if (rB) b5 = LO8;
            h8 t12 = MAX2(b1, b2), t34 = MAX2(b3, b4);
            h8 Mr0 = MAX2(b0, t12), Mr1 = MAX2(t12, b3);
            h8 Mr2 = MAX2(b2, t34), Mr3 = MAX2(t34, b5);
            if (cR) { Mr0 = LO8; Mr1 = LO8; Mr2 = LO8; Mr3 = LO8; }
            h8 o0 = MAX2(Mc0, MAX2(shl1(Mc0, dw3(Ml0)), shr1(Mc0, dw0(Mr0))));
            h8 o1 = MAX2(Mc1, MAX2(shl1(Mc1, dw3(Ml1)), shr1(Mc1, dw0(Mr1))));
            h8 o2 = MAX2(Mc2, MAX2(shl1(Mc2, dw3(Ml2)), shr1(Mc2, dw0(Mr2))));
            h8 o3 = MAX2(Mc3, MAX2(shl1(Mc3, dw3(Ml3)), shr1(Mc3, dw0(Mr3))));
            h8 d0 = MAX2(imv[0] - o0, Z8);
            h8 d1 = MAX2(imv[1] - o1, Z8);
            h8 d2 = MAX2(imv[2] - o2, Z8);
            h8 d3 = MAX2(imv[3] - o3, Z8);
            if (L == 1) { sk[0] = d0; sk[1] = d1; sk[2] = d2; sk[3] = d3; }
            else {
                sk[0] = sk[0] + MAX2(d0 - sk[0] * d0, Z8);
                sk[1] = sk[1] + MAX2(d1 - sk[1] * d1, Z8);
                sk[2] = sk[2] + MAX2(d2 - sk[2] * d2, Z8);
                sk[3] = sk[3] + MAX2(d3 - sk[3] * d3, Z8);
            }
            imv[0] = nm0; imv[1] = nm1; imv[2] = nm2; imv[3] = nm3;
        }
        // T-open (bits): dilate = OR 3x3; sk |= im & ~open
        if (has_to) {
            u32 m0 = bmT[tob - BMP], m1 = bmT[tob], m2 = bmT[tob + BMP];
            u32 m3 = bmT[tob + 2 * BMP], m4 = bmT[tob + 3 * BMP], m5 = bmT[tob + 4 * BMP];
            u32 nm0 = m1, nm1 = m2, nm2 = m3, nm3 = m4;
            u32 l0 = bmT[tob - BMP - 1], l1 = bmT[tob - 1], l2 = bmT[tob + BMP - 1];
            u32 l3 = bmT[tob + 2 * BMP - 1], l4 = bmT[tob + 3 * BMP - 1], l5 = bmT[tob + 4 * BMP - 1];
            u32 r0 = bmT[tob - BMP + 1], r1 = bmT[tob + 1], r2 = bmT[tob + BMP + 1];
            u32 r3 = bmT[tob + 2 * BMP + 1], r4 = bmT[tob + 3 * BMP + 1], r5 = bmT[tob + 4 * BMP + 1];
            if (trT) { m0 = 0; l0 = 0; r0 = 0; }
            if (trB) { m5 = 0; l5 = 0; r5 = 0; }
            if (tcL) { l0 = 0; l1 = 0; l2 = 0; l3 = 0; l4 = 0; l5 = 0; }
            if (tcR) { r0 = 0; r1 = 0; r2 = 0; r3 = 0; r4 = 0; r5 = 0; }
            u32 q12 = m1 | m2, q34 = m3 | m4;
            u32 Vc0 = m0 | q12, Vc1 = q12 | m3, Vc2 = m2 | q34, Vc3 = q34 | m5;
            u32 s12 = l1 | l2, s34 = l3 | l4;
            u32 Vl0 = l0 | s12, Vl1 = s12 | l3, Vl2 = l2 | s34, Vl3 = s34 | l5;
            u32 t12 = r1 | r2, t34 = r3 | r4;
            u32 Vr0 = r0 | t12, Vr1 = t12 | r3, Vr2 = r2 | t34, Vr3 = t34 | r5;
            u32 o0 = Vc0 | fsh(Vc0, Vl0, 31) | fsh(Vr0, Vc0, 1);
            u32 o1 = Vc1 | fsh(Vc1, Vl1, 31) | fsh(Vr1, Vc1, 1);
            u32 o2 = Vc2 | fsh(Vc2, Vl2, 31) | fsh(Vr2, Vc2, 1);
            u32 o3 = Vc3 | fsh(Vc3, Vl3, 31) | fsh(Vr3, Vc3, 1);
            tsk[0] |= timv[0] & ~o0;
            tsk[1] |= timv[1] & ~o1;
            tsk[2] |= timv[2] & ~o2;
            tsk[3] |= timv[3] & ~o3;
            timv[0] = nm0; timv[1] = nm1; timv[2] = nm2; timv[3] = nm3;
        }
        // no barrier: open reads and next round's erode reads are both level L
    }

    // ---- final: T publishes skel bits; O-open computes I, So ----
    __syncthreads();
    float I = 0.f, So = 0.f, St = 0.f;
    if (has_to) {
#pragma unroll
        for (int k = 0; k < 4; ++k) {
            pub[(tp << 2) + k] = tsk[k];
            St += (float)__popc(tsk[k]);
        }
    }
    __syncthreads();
    if (has_o) {
        int tt = (opr << 2) + (oc >> 2);
        int sh = (oc & 3) * 8;
#pragma unroll
        for (int k = 0; k < 4; ++k) {
            u32 w = pub[(tt << 2) + k] >> sh;
#pragma unroll
            for (int j = 0; j < 8; ++j) {
                float a = (float)sk[k][j];
                So += a;
                if ((w >> j) & 1u) I += a;
            }
        }
    }

    // ---- block reduce 6 values (16 waves) ----
    float v6[6] = {d_inter, d_card, d_st, I, So, St};
#pragma unroll
    for (int q = 0; q < 6; ++q)
        for (int off = 32; off > 0; off >>= 1) v6[q] += __shfl_down(v6[q], off);
    int lane = tid & 63, w = tid >> 6;
    if (lane == 0) {
#pragma unroll
        for (int q = 0; q < 6; ++q) red[w * 6 + q] = v6[q];
    }
    __syncthreads();
    if (tid == 0) {
        int bid = (blockIdx.z * gridDim.y + blockIdx.y) * gridDim.x + blockIdx.x;
#pragma unroll
        for (int q = 0; q < 6; ++q) {
            float s = 0.f;
#pragma unroll
            for (int ww = 0; ww < 16; ++ww) s += red[ww * 6 + q];
            partials[q * NBLK + bid] = s;
        }
    }
}

__global__ __launch_bounds__(1024) void final_kernel(const float* __restrict__ partials,
                                                     float* __restrict__ out) {
    float s[6] = {0.f, 0.f, 0.f, 0.f, 0.f, 0.f};
    for (int i = threadIdx.x; i < NBLK; i += 1024) {
#pragma unroll
        for (int q = 0; q < 6; ++q) s[q] += partials[q * NBLK + i];
    }
#pragma unroll
    for (int q = 0; q < 6; ++q)
        for (int off = 32; off > 0; off >>= 1) s[q] += __shfl_down(s[q], off);
    __shared__ float red[96];
    int lane = threadIdx.x & 63, w = threadIdx.x >> 6;
    if (lane == 0) {
#pragma unroll
        for (int q = 0; q < 6; ++q) red[w * 6 + q] = s[q];
    }
    __syncthreads();
    if (threadIdx.x == 0) {
        float t[6];
#pragma unroll
        for (int q = 0; q < 6; ++q) {
            float a = 0.f;
#pragma unroll
            for (int ww = 0; ww < 16; ++ww) a += red[ww * 6 + q];
            t[q] = a;
        }
        float inter = t[0], card = t[1], sumt = t[2];
        float I = t[3], So = t[4], St = t[5];
        float score_d = (2.0f * inter + 1.0f) / fmaxf(card + 1.0f, 1e-7f);
        float dice = (1.0f - score_d) * (sumt > 0.0f ? 1.0f : 0.0f);
        float tprec = (I + 1.0f) / (So + 1.0f);
        float tsens = (I + 1.0f) / (St + 1.0f);
        float score_c = 2.0f * (tprec * tsens) / (tprec + tsens);
        float cl = (1.0f - score_c) * (St > 0.0f ? 1.0f : 0.0f);
        out[0] = 0.5f * dice + 0.5f * cl;
    }
}

extern "C" void kernel_launch(void* const* d_in, const int* in_sizes, int n_in,
                              void* d_out, int out_size, void* d_ws, size_t ws_size,
                              hipStream_t stream) {
    const float* logits = (const float*)d_in[0];
    const int* target = (const int*)d_in[1];
    float* out = (float*)d_out;
    float* partials = (float*)d_ws;  // 6*NBLK floats, fully overwritten each call

    dim3 grid(NBX, NBY, BATCH);
    cldice_mega_kernel<<<grid, NT, 0, stream>>>(logits, target, partials);
    final_kernel<<<1, 1024, 0, stream>>>(partials, out);
}

// Round 5
// 169.377 us; speedup vs baseline: 1.3504x; 1.0700x over previous
//
#include <hip/hip_runtime.h>
#include <math.h>

// clDice loss, fully fused (R20 = R19 with the macro self-shadow bug fixed).
// R19 postmortem: `const int L = (LV);` inside PHASE() invoked as PHASE(L,..)
// expands to `const int L = (L);` -- self-init from the shadowed (uninit)
// inner L; all phase gates ran on garbage -> absmax 0.121. Renamed to PL.
// Structure (audited sound): bufO/bmT ping-pong; phase p = { erode_p: rd lv
// p-1 from X, wr lv p to Y || open_{p-1}: rd lv p-1 from X } -> ONE barrier
// per phase, 12 phases (erode 1..11 via e_M cap, open 2..12 -> delta_0..10).
// Per-pixel cone + activity monotonicity: consumed pixel at phase p has dist
// >= p-1 -> its quad (e_M >= dist) wrote it into X at phase p-1. Never-written
// cells (rows 0/87 of buf[1]) are read only into untrusted lanes (per-lane
// containment; AMD v_pk_min/max drop NaN operands). Waves disjoint:
// O-erode 0-6, O-open 8-11, T-erode 12-14, T-open 15. T side bitboard (exact).
// Tile 128x64, aperture 160x88, LDS ~60.5KB -> 2 blocks/CU.

#define HH 1024
#define WW 1024
#define BATCH 8
#define HW (HH * WW)
#define NITER 10
#define TW 128
#define TH 64
#define AH 88                 // aperture rows (halo 12)
#define CXC 20                // h8 cells per row (160 px, halo 16 = 2 cells)
#define NCELL (AH * CXC)      // 1760
#define BMP 6                 // T bitmap pitch (dwords/row, 192 bits)
#define NQO 440               // O erode quads (22 x 20)
#define NT 1024               // 16 waves
#define NBX 8
#define NBY 16
#define NBLK (NBX * NBY * BATCH)  // 1024

typedef _Float16 h8 __attribute__((ext_vector_type(8)));
typedef unsigned int u32;
typedef unsigned long long u64;
typedef u32 u4v __attribute__((ext_vector_type(4)));

#define MIN2(a, b) __builtin_elementwise_min(a, b)
#define MAX2(a, b) __builtin_elementwise_max(a, b)

__device__ __forceinline__ u32 alignb(u32 hi, u32 lo) {
    return (u32)((((u64)hi << 32) | lo) >> 16);
}
__device__ __forceinline__ u32 fsh(u32 hi, u32 lo, int s) {
    return (u32)((((u64)hi << 32) | lo) >> s);  // v_alignbit_b32
}
__device__ __forceinline__ u32 dw0(h8 v) { return __builtin_bit_cast(u4v, v).x; }
__device__ __forceinline__ u32 dw3(h8 v) { return __builtin_bit_cast(u4v, v).w; }
// result[j]=v[j-1], result[0]=left-neighbor elem7 (hi half of l3)
__device__ __forceinline__ h8 shl1(h8 v, u32 l3) {
    u4v d = __builtin_bit_cast(u4v, v);
    u4v r;
    r.x = alignb(d.x, l3); r.y = alignb(d.y, d.x);
    r.z = alignb(d.z, d.y); r.w = alignb(d.w, d.z);
    return __builtin_bit_cast(h8, r);
}
// result[j]=v[j+1], result[7]=right-neighbor elem0 (lo half of r0d)
__device__ __forceinline__ h8 shr1(h8 v, u32 r0d) {
    u4v d = __builtin_bit_cast(u4v, v);
    u4v r;
    r.x = alignb(d.y, d.x); r.y = alignb(d.z, d.y);
    r.z = alignb(d.w, d.z); r.w = alignb(r0d, d.w);
    return __builtin_bit_cast(h8, r);
}
__device__ __forceinline__ float sigm(float x) { return 1.0f / (1.0f + __expf(-x)); }
__device__ __forceinline__ int imin(int a, int b) { return a < b ? a : b; }
__device__ __forceinline__ int imax(int a, int b) { return a > b ? a : b; }

__global__ __launch_bounds__(NT) void cldice_mega_kernel(const float* __restrict__ logits,
                                                         const int* __restrict__ target,
                                                         float* __restrict__ partials) {
    __shared__ __align__(16) h8 bufO[2][NCELL];   // 2 x 28.2 KB ping-pong
    __shared__ u32 bmT[2][AH * BMP];              // 2 x 2.1 KB bitboard
    __shared__ u32 pub[256];                      // skT publish (64 tasks x 4)
    __shared__ float red[96];

    const int tid = threadIdx.x;
    const int img = blockIdx.z;
    const int x0 = blockIdx.x * TW, y0 = blockIdx.y * TH;

    const _Float16 HIF = (_Float16)__builtin_inff();
    const h8 HI8 = (h8)HIF;
    const h8 LO8 = (h8)(-HIF);
    const h8 Z8 = (h8)(_Float16)0;

    // ---- O-erode geometry (440 tasks, tid 0..439) ----
    const bool has_e = tid < NQO;
    int e_base = CXC, e_M = 0;
    bool e_rok[4] = {false, false, false, false};
    if (has_e) {
        int q = tid / 20, c = tid - (tid / 20) * 20;
        int r = 1 + 4 * q;
        if (r > 83) r = 83;                 // last quad rows 83..86
        e_base = r * CXC + c;
        int cMx = imin(8 * c + 7, 159 - 8 * c);
#pragma unroll
        for (int k = 0; k < 4; ++k)
            e_M = imax(e_M, imin(imin(r + k, 87 - (r + k)), cMx));
        e_M = imin(e_M, NITER + 1);         // erode runs phases 1..11 only
        bool colOOB = (x0 == 0 && c < 2) || (x0 == WW - TW && c >= 18);
#pragma unroll
        for (int k = 0; k < 4; ++k)
            e_rok[k] = !colOOB && ((unsigned)(y0 - 12 + r + k) < HH);
    }

    // ---- O-open geometry (256 tasks, tid 512..767) ----
    const bool has_o = (tid >= 512) && (tid < 768);
    const int op = tid & 255;
    const int opr = op >> 4, oc = op & 15;      // opr 0..15, oc 0..15
    const int orow = 12 + 4 * opr;              // rows orow..orow+3 (12..75)
    const int ob = orow * CXC + 2 + oc;
    const bool rT = (y0 == 0 && opr == 0);
    const bool rB = (y0 == HH - TH && opr == 15);
    const bool cL = (x0 == 0 && oc == 0);
    const bool cR = (x0 == WW - TW && oc == 15);

    // ---- T-erode-bit geometry (132 tasks, tid 768..899) ----
    const bool has_te = (tid >= 768) && (tid < 768 + 22 * BMP);
    int tb = BMP, te_M = 0;
    u32 oobm = 0;
    bool trok[4] = {false, false, false, false};
    if (has_te) {
        int p = tid - 768;
        int q = p / BMP, c = p - (p / BMP) * BMP;
        int r = 1 + 4 * q;
        if (r > 83) r = 83;
        tb = r * BMP + c;
        // dword c covers aperture px [32c-16, 32c+15]
        int pxlo = imax(32 * c - 16, 0), pxhi = imin(32 * c + 15, 159);
        int cMx = imin(pxhi, 159 - pxlo);
#pragma unroll
        for (int k = 0; k < 4; ++k)
            te_M = imax(te_M, imin(imin(r + k, 87 - (r + k)), cMx));
        te_M = imin(te_M, NITER + 1);
        if (c == 0) oobm |= 0x0000FFFFu;                 // pre-pad bits
        if (c == 5) oobm |= 0xFFFF0000u;                 // post-pad bits
        if (x0 == 0 && c == 0) oobm = 0xFFFFFFFFu;       // px 0..15 OOB
        if (x0 == WW - TW && c == 5) oobm = 0xFFFFFFFFu; // px 144..159 OOB
#pragma unroll
        for (int k = 0; k < 4; ++k)
            trok[k] = (unsigned)(y0 - 12 + r + k) < HH;
    }

    // ---- T-open-bit geometry (64 tasks, tid 960..1023) ----
    const bool has_to = tid >= 960;
    const int tp = tid - 960;
    const int topr = (tp >> 2) & 15, td = (tp & 3) + 1;  // dwords 1..4
    const int torow = 12 + 4 * topr;
    const int tob = torow * BMP + td;
    const bool trT = (y0 == 0 && topr == 0);
    const bool trB = (y0 == HH - TH && topr == 15);
    const bool tcL = (x0 == 0 && td == 1);
    const bool tcR = (x0 == WW - TW && td == 4);

    // ---- bitmap pads: bits 0-15 / 176-191 of each row = 1 (erode +inf) ----
    if (tid < AH) {
        unsigned short* p16 = (unsigned short*)bmT[0];
        p16[tid * 12 + 0] = 0xFFFFu;
        p16[tid * 12 + 11] = 0xFFFFu;
        unsigned short* q16 = (unsigned short*)bmT[1];
        q16[tid * 12 + 0] = 0xFFFFu;
        q16[tid * 12 + 11] = 0xFFFFu;
    }

    // ---- load: O image (sigmoid h8), T bitboard -> buffers [0]; dice ----
    float d_inter = 0.f, d_card = 0.f, d_st = 0.f;
#pragma unroll
    for (int s = 0; s < 2; ++s) {
        int li = tid + NT * s;
        if (li < NCELL) {
            int r = li / CXC, c = li - (li / CXC) * CXC;
            int gy = y0 - 12 + r, gx = x0 - 16 + 8 * c;
            bool gyok = (unsigned)gy < HH;
            float vo[8];
            u32 tb8 = 0;  // 8 target bits (1 = fg or OOB)
            if (gyok && gx >= 0 && gx + 7 < WW) {
                int g = img * HW + gy * WW + gx;
                float4 a = *(const float4*)(logits + g);
                float4 b = *(const float4*)(logits + g + 4);
                vo[0] = sigm(a.x); vo[1] = sigm(a.y); vo[2] = sigm(a.z); vo[3] = sigm(a.w);
                vo[4] = sigm(b.x); vo[5] = sigm(b.y); vo[6] = sigm(b.z); vo[7] = sigm(b.w);
                int4 p = *(const int4*)(target + g);
                int4 q = *(const int4*)(target + g + 4);
                tb8 = (p.x != 0 ? 1u : 0u) | (p.y != 0 ? 2u : 0u) |
                      (p.z != 0 ? 4u : 0u) | (p.w != 0 ? 8u : 0u) |
                      (q.x != 0 ? 16u : 0u) | (q.y != 0 ? 32u : 0u) |
                      (q.z != 0 ? 64u : 0u) | (q.w != 0 ? 128u : 0u);
            } else {
#pragma unroll
                for (int j = 0; j < 8; ++j) {
                    int gxx = gx + j;
                    if (gyok && (unsigned)gxx < WW) {
                        int g = img * HW + gy * WW + gxx;
                        vo[j] = sigm(logits[g]);
                        tb8 |= (target[g] != 0 ? 1u : 0u) << j;
                    } else { vo[j] = INFINITY; tb8 |= 1u << j; }
                }
            }
            h8 ho;
#pragma unroll
            for (int j = 0; j < 8; ++j) ho[j] = (_Float16)vo[j];
            bufO[0][li] = ho;
            ((unsigned char*)bmT[0])[r * 24 + 2 + c] = (unsigned char)tb8;
            if (r >= 12 && r < 76 && c >= 2 && c < 18) {
#pragma unroll
                for (int j = 0; j < 8; ++j) {
                    float t = (float)((tb8 >> j) & 1u);
                    d_inter += t * vo[j];
                    d_card += vo[j] + t;
                    d_st += t;
                }
            }
        }
    }
    __syncthreads();
    h8 imv[4], sk[4];
    if (has_o) {
#pragma unroll
        for (int k = 0; k < 4; ++k) imv[k] = bufO[0][ob + k * CXC];
    }
#pragma unroll
    for (int k = 0; k < 4; ++k) sk[k] = Z8;
    u32 timv[4] = {0, 0, 0, 0}, tsk[4] = {0, 0, 0, 0};
    if (has_to) {
#pragma unroll
        for (int k = 0; k < 4; ++k) timv[k] = bmT[0][tob + k * BMP];
    }

    // ---- phases p=1..12: erode_p (rd->wr) || open_{p-1} (rd); 1 barrier ----
    // NOTE: macro-internal level var is PL (NOT L) -- PHASE(L,..) with an
    // internal `const int L = (LV);` self-initializes from the shadowed
    // declaration (R19 bug).
#define PHASE(LV, rdO, wrO, rdT, wrT)                                              \
    {                                                                              \
        const int PL = (LV);                                                       \
        /* O-erode: read lv PL-1 from rdO, write lv PL to wrO */                   \
        if (has_e && PL <= e_M) {                                                  \
            const h8* b = (rdO);                                                   \
            h8 u  = b[e_base - CXC];                                               \
            h8 c0 = b[e_base],           c1 = b[e_base + CXC];                     \
            h8 c2 = b[e_base + 2 * CXC], c3 = b[e_base + 3 * CXC];                 \
            h8 d  = b[e_base + 4 * CXC];                                           \
            h8 l0 = b[e_base - 1],           l1 = b[e_base + CXC - 1];             \
            h8 l2 = b[e_base + 2 * CXC - 1], l3 = b[e_base + 3 * CXC - 1];         \
            h8 r0 = b[e_base + 1],           r1 = b[e_base + CXC + 1];             \
            h8 r2 = b[e_base + 2 * CXC + 1], r3 = b[e_base + 3 * CXC + 1];         \
            h8 p01 = MIN2(c0, c1), p12 = MIN2(c1, c2), p23 = MIN2(c2, c3);         \
            h8 v0 = MIN2(u, p01), v1 = MIN2(p01, c2);                              \
            h8 v2 = MIN2(p12, c3), v3 = MIN2(p23, d);                              \
            h8 eo0 = MIN2(v0, MIN2(shl1(c0, dw3(l0)), shr1(c0, dw0(r0))));         \
            h8 eo1 = MIN2(v1, MIN2(shl1(c1, dw3(l1)), shr1(c1, dw0(r1))));         \
            h8 eo2 = MIN2(v2, MIN2(shl1(c2, dw3(l2)), shr1(c2, dw0(r2))));         \
            h8 eo3 = MIN2(v3, MIN2(shl1(c3, dw3(l3)), shr1(c3, dw0(r3))));         \
            (wrO)[e_base]           = e_rok[0] ? eo0 : HI8;                        \
            (wrO)[e_base + CXC]     = e_rok[1] ? eo1 : HI8;                        \
            (wrO)[e_base + 2 * CXC] = e_rok[2] ? eo2 : HI8;                        \
            (wrO)[e_base + 3 * CXC] = e_rok[3] ? eo3 : HI8;                        \
        }                                                                          \
        /* T-erode bits: AND of 5-px cross */                                      \
        if (has_te && PL <= te_M) {                                                \
            const u32* bt = (rdT);                                                 \
            u32 m0 = bt[tb - BMP], m1 = bt[tb], m2 = bt[tb + BMP];                 \
            u32 m3 = bt[tb + 2 * BMP], m4 = bt[tb + 3 * BMP], m5 = bt[tb + 4 * BMP]; \
            u32 lw0 = bt[tb - 1],           lw1 = bt[tb + BMP - 1];                \
            u32 lw2 = bt[tb + 2 * BMP - 1], lw3 = bt[tb + 3 * BMP - 1];            \
            u32 rw0 = bt[tb + 1],           rw1 = bt[tb + BMP + 1];                \
            u32 rw2 = bt[tb + 2 * BMP + 1], rw3 = bt[tb + 3 * BMP + 1];            \
            u32 p12 = m1 & m2, p23 = m2 & m3, p34 = m3 & m4;                       \
            u32 v0 = m0 & p12, v1 = p12 & m3, v2 = p23 & m4, v3 = p34 & m5;        \
            u32 et0 = v0 & fsh(m1, lw0, 31) & fsh(rw0, m1, 1);                     \
            u32 et1 = v1 & fsh(m2, lw1, 31) & fsh(rw1, m2, 1);                     \
            u32 et2 = v2 & fsh(m3, lw2, 31) & fsh(rw2, m3, 1);                     \
            u32 et3 = v3 & fsh(m4, lw3, 31) & fsh(rw3, m4, 1);                     \
            (wrT)[tb]           = trok[0] ? (et0 | oobm) : 0xFFFFFFFFu;            \
            (wrT)[tb + BMP]     = trok[1] ? (et1 | oobm) : 0xFFFFFFFFu;            \
            (wrT)[tb + 2 * BMP] = trok[2] ? (et2 | oobm) : 0xFFFFFFFFu;            \
            (wrT)[tb + 3 * BMP] = trok[3] ? (et3 | oobm) : 0xFFFFFFFFu;            \
        }                                                                          \
        /* O-open_{PL-1}: read lv PL-1 from rdO; delta_{PL-2}; imv chain */        \
        if (has_o && PL >= 2) {                                                    \
            const h8* b = (rdO);                                                   \
            h8 m0 = b[ob - CXC], m1 = b[ob], m2 = b[ob + CXC];                     \
            h8 m3 = b[ob + 2 * CXC], m4 = b[ob + 3 * CXC], m5 = b[ob + 4 * CXC];  \
            h8 nm0 = m1, nm1 = m2, nm2 = m3, nm3 = m4;                             \
            if (rT) m0 = LO8;                                                      \
            if (rB) m5 = LO8;                                                      \
            h8 q12 = MAX2(m1, m2), q34 = MAX2(m3, m4);                             \
            h8 Mc0 = MAX2(m0, q12), Mc1 = MAX2(q12, m3);                           \
            h8 Mc2 = MAX2(m2, q34), Mc3 = MAX2(q34, m5);                           \
            h8 a0 = b[ob - CXC - 1], a1 = b[ob - 1], a2 = b[ob + CXC - 1];         \
            h8 a3 = b[ob + 2 * CXC - 1], a4 = b[ob + 3 * CXC - 1];                 \
            h8 a5 = b[ob + 4 * CXC - 1];                                           \
            if (rT) a0 = LO8;                                                      \
            if (rB) a5 = LO8;                                                      \
            h8 s12 = MAX2(a1, a2), s34 = MAX2(a3, a4);                             \
            h8 Ml0 = MAX2(a0, s12), Ml1 = MAX2(s12, a3);                           \
            h8 Ml2 = MAX2(a2, s34), Ml3 = MAX2(s34, a5);                           \
            if (cL) { Ml0 = LO8; Ml1 = LO8; Ml2 = LO8; Ml3 = LO8; }                \
            h8 b0 = b[ob - CXC + 1], b1 = b[ob + 1], b2 = b[ob + CXC + 1];         \
            h8 b3 = b[ob + 2 * CXC + 1], b4 = b[ob + 3 * CXC + 1];                 \
            h8 b5 = b[ob + 4 * CXC + 1];                                           \
            if (rT) b0 = LO8;                                                      \
            if (rB) b5 = LO8;                                                      \
            h8 t12 = MAX2(b1, b2), t34 = MAX2(b3, b4);                             \
            h8 Mr0 = MAX2(b0, t12), Mr1 = MAX2(t12, b3);                           \
            h8 Mr2 = MAX2(b2, t34), Mr3 = MAX2(t34, b5);                           \
            if (cR) { Mr0 = LO8; Mr1 = LO8; Mr2 = LO8; Mr3 = LO8; }                \
            h8 o0 = MAX2(Mc0, MAX2(shl1(Mc0, dw3(Ml0)), shr1(Mc0, dw0(Mr0))));     \
            h8 o1 = MAX2(Mc1, MAX2(shl1(Mc1, dw3(Ml1)), shr1(Mc1, dw0(Mr1))));     \
            h8 o2 = MAX2(Mc2, MAX2(shl1(Mc2, dw3(Ml2)), shr1(Mc2, dw0(Mr2))));     \
            h8 o3 = MAX2(Mc3, MAX2(shl1(Mc3, dw3(Ml3)), shr1(Mc3, dw0(Mr3))));     \
            h8 d0 = MAX2(imv[0] - o0, Z8);                                         \
            h8 d1 = MAX2(imv[1] - o1, Z8);                                         \
            h8 d2 = MAX2(imv[2] - o2, Z8);                                         \
            h8 d3 = MAX2(imv[3] - o3, Z8);                                         \
            if (PL == 2) { sk[0] = d0; sk[1] = d1; sk[2] = d2; sk[3] = d3; }       \
            else {                                                                 \
                sk[0] = sk[0] + MAX2(d0 - sk[0] * d0, Z8);                         \
                sk[1] = sk[1] + MAX2(d1 - sk[1] * d1, Z8);                         \
                sk[2] = sk[2] + MAX2(d2 - sk[2] * d2, Z8);                         \
                sk[3] = sk[3] + MAX2(d3 - sk[3] * d3, Z8);                         \
            }                                                                      \
            imv[0] = nm0; imv[1] = nm1; imv[2] = nm2; imv[3] = nm3;                \
        }                                                                          \
        /* T-open bits: dilate = OR 3x3; tsk |= timv & ~open */                    \
        if (has_to && PL >= 2) {                                                   \
            const u32* bt = (rdT);                                                 \
            u32 m0 = bt[tob - BMP], m1 = bt[tob], m2 = bt[tob + BMP];              \
            u32 m3 = bt[tob + 2 * BMP], m4 = bt[tob + 3 * BMP];                    \
            u32 m5 = bt[tob + 4 * BMP];                                            \
            u32 nm0 = m1, nm1 = m2, nm2 = m3, nm3 = m4;                            \
            u32 l0 = bt[tob - BMP - 1], l1 = bt[tob - 1], l2 = bt[tob + BMP - 1];  \
            u32 l3 = bt[tob + 2 * BMP - 1], l4 = bt[tob + 3 * BMP - 1];            \
            u32 l5 = bt[tob + 4 * BMP - 1];                                        \
            u32 r0 = bt[tob - BMP + 1], r1 = bt[tob + 1], r2 = bt[tob + BMP + 1];  \
            u32 r3 = bt[tob + 2 * BMP + 1], r4 = bt[tob + 3 * BMP + 1];            \
            u32 r5 = bt[tob + 4 * BMP + 1];                                        \
            if (trT) { m0 = 0; l0 = 0; r0 = 0; }                                   \
            if (trB) { m5 = 0; l5 = 0; r5 = 0; }                                   \
            if (tcL) { l0 = 0; l1 = 0; l2 = 0; l3 = 0; l4 = 0; l5 = 0; }           \
            if (tcR) { r0 = 0; r1 = 0; r2 = 0; r3 = 0; r4 = 0; r5 = 0; }           \
            u32 q12 = m1 | m2, q34 = m3 | m4;                                      \
            u32 Vc0 = m0 | q12, Vc1 = q12 | m3, Vc2 = m2 | q34, Vc3 = q34 | m5;    \
            u32 s12 = l1 | l2, s34 = l3 | l4;                                      \
            u32 Vl0 = l0 | s12, Vl1 = s12 | l3, Vl2 = l2 | s34, Vl3 = s34 | l5;    \
            u32 t12 = r1 | r2, t34 = r3 | r4;                                      \
            u32 Vr0 = r0 | t12, Vr1 = t12 | r3, Vr2 = r2 | t34, Vr3 = t34 | r5;    \
            u32 o0 = Vc0 | fsh(Vc0, Vl0, 31) | fsh(Vr0, Vc0, 1);                   \
            u32 o1 = Vc1 | fsh(Vc1, Vl1, 31) | fsh(Vr1, Vc1, 1);                   \
            u32 o2 = Vc2 | fsh(Vc2, Vl2, 31) | fsh(Vr2, Vc2, 1);                   \
            u32 o3 = Vc3 | fsh(Vc3, Vl3, 31) | fsh(Vr3, Vc3, 1);                   \
            tsk[0] |= timv[0] & ~o0;                                               \
            tsk[1] |= timv[1] & ~o1;                                               \
            tsk[2] |= timv[2] & ~o2;                                               \
            tsk[3] |= timv[3] & ~o3;                                               \
            timv[0] = nm0; timv[1] = nm1; timv[2] = nm2; timv[3] = nm3;            \
        }                                                                          \
        __syncthreads();                                                           \
    }

    for (int L = 1; L <= NITER + 2; L += 2) {
        PHASE(L,     bufO[0], bufO[1], bmT[0], bmT[1])
        PHASE(L + 1, bufO[1], bufO[0], bmT[1], bmT[0])
    }
#undef PHASE

    // ---- final: T publishes skel bits; O-open computes I, So ----
    float I = 0.f, So = 0.f, St = 0.f;
    if (has_to) {
#pragma unroll
        for (int k = 0; k < 4; ++k) {
            pub[(tp << 2) + k] = tsk[k];
            St += (float)__popc(tsk[k]);
        }
    }
    __syncthreads();
    if (has_o) {
        int tt = (opr << 2) + (oc >> 2);
        int sh = (oc & 3) * 8;
#pragma unroll
        for (int k = 0; k < 4; ++k) {
            u32 w = pub[(tt << 2) + k] >> sh;
#pragma unroll
            for (int j = 0; j < 8; ++j) {
                float a = (float)sk[k][j];
                So += a;
                if ((w >> j) & 1u) I += a;
            }
        }
    }

    // ---- block reduce 6 values (16 waves) ----
    float v6[6] = {d_inter, d_card, d_st, I, So, St};
#pragma unroll
    for (int q = 0; q < 6; ++q)
        for (int off = 32; off > 0; off >>= 1) v6[q] += __shfl_down(v6[q], off);
    int lane = tid & 63, w = tid >> 6;
    if (lane == 0) {
#pragma unroll
        for (int q = 0; q < 6; ++q) red[w * 6 + q] = v6[q];
    }
    __syncthreads();
    if (tid == 0) {
        int bid = (blockIdx.z * gridDim.y + blockIdx.y) * gridDim.x + blockIdx.x;
#pragma unroll
        for (int q = 0; q < 6; ++q) {
            float s = 0.f;
#pragma unroll
            for (int ww = 0; ww < 16; ++ww) s += red[ww * 6 + q];
            partials[q * NBLK + bid] = s;
        }
    }
}

__global__ __launch_bounds__(1024) void final_kernel(const float* __restrict__ partials,
                                                     float* __restrict__ out) {
    float s[6] = {0.f, 0.f, 0.f, 0.f, 0.f, 0.f};
    for (int i = threadIdx.x; i < NBLK; i += 1024) {
#pragma unroll
        for (int q = 0; q < 6; ++q) s[q] += partials[q * NBLK + i];
    }
#pragma unroll
    for (int q = 0; q < 6; ++q)
        for (int off = 32; off > 0; off >>= 1) s[q] += __shfl_down(s[q], off);
    __shared__ float red[96];
    int lane = threadIdx.x & 63, w = threadIdx.x >> 6;
    if (lane == 0) {
#pragma unroll
        for (int q = 0; q < 6; ++q) red[w * 6 + q] = s[q];
    }
    __syncthreads();
    if (threadIdx.x == 0) {
        float t[6];
#pragma unroll
        for (int q = 0; q < 6; ++q) {
            float a = 0.f;
#pragma unroll
            for (int ww = 0; ww < 16; ++ww) a += red[ww * 6 + q];
            t[q] = a;
        }
        float inter = t[0], card = t[1], sumt = t[2];
        float I = t[3], So = t[4], St = t[5];
        float score_d = (2.0f * inter + 1.0f) / fmaxf(card + 1.0f, 1e-7f);
        float dice = (1.0f - score_d) * (sumt > 0.0f ? 1.0f : 0.0f);
        float tprec = (I + 1.0f) / (So + 1.0f);
        float tsens = (I + 1.0f) / (St + 1.0f);
        float score_c = 2.0f * (tprec * tsens) / (tprec + tsens);
        float cl = (1.0f - score_c) * (St > 0.0f ? 1.0f : 0.0f);
        out[0] = 0.5f * dice + 0.5f * cl;
    }
}

extern "C" void kernel_launch(void* const* d_in, const int* in_sizes, int n_in,
                              void* d_out, int out_size, void* d_ws, size_t ws_size,
                              hipStream_t stream) {
    const float* logits = (const float*)d_in[0];
    const int* target = (const int*)d_in[1];
    float* out = (float*)d_out;
    float* partials = (float*)d_ws;  // 6*NBLK floats, fully overwritten each call

    dim3 grid(NBX, NBY, BATCH);
    cldice_mega_kernel<<<grid, NT, 0, stream>>>(logits, target, partials);
    final_kernel<<<1, 1024, 0, stream>>>(partials, out);
}